// Round 1
// baseline (285.261 us; speedup 1.0000x reference)
//
#include <hip/hip_runtime.h>
#include <hip/hip_bf16.h>
#include <math.h>

// Problem constants
#define BB 256
#define TT 512
#define EE 128
#define HH 128
#define NC 4
#define MM (BB * TT)   // 131072 rows of the input GEMM

typedef __bf16 bf16x8 __attribute__((ext_vector_type(8)));
typedef __bf16 bf16x4 __attribute__((ext_vector_type(4)));
typedef float  f32x4  __attribute__((ext_vector_type(4)));
typedef float  f32x2  __attribute__((ext_vector_type(2)));

// Branch-free tanh: 1 - 2/(1+e^{2x}) with e^{2x} = exp2(2*log2e*x).
__device__ __forceinline__ float fast_tanh(float x) {
    float t = __builtin_amdgcn_exp2f(x * 2.885390081777927f);
    return 1.f - 2.f * __builtin_amdgcn_rcpf(1.f + t);
}

// ---------------------------------------------------------------------------
// Kernel 1: x_proj[m,h] = sum_e emb[x[m],e] * W_ih[h,e] + b_ih[h] + b_hh[h]
// Split-bf16 GEMM (AhWh + AlWh + AhWl). K processed in 2 halves of 64 with
// half-size LDS buffers (~74 KB total) so 2 blocks/CU actually fit.
// (unchanged this round)
// ---------------------------------------------------------------------------
template <typename XPT>
__global__ __launch_bounds__(256, 2) void embed_gemm(
    const int* __restrict__ x, const float* __restrict__ emb,
    const float* __restrict__ Wih, const float* __restrict__ bih,
    const float* __restrict__ bhh, XPT* __restrict__ xpout)
{
    const int tid = threadIdx.x;
    const int m0  = blockIdx.x * 128;

    const int LDA = 72;  // bf16 units per 64-wide half row (144 B, 16B-aligned)
    __shared__ __bf16 Ah[128 * 72];
    __shared__ __bf16 Al[128 * 72];
    __shared__ __bf16 Wh[128 * 72];
    __shared__ __bf16 Wl[128 * 72];
    __shared__ float  bias_s[128];
    __shared__ int    gix[128];

    if (tid < 128) {
        gix[tid]    = x[m0 + tid];
        bias_s[tid] = bih[tid] + bhh[tid];
    }

    const int lane = tid & 63, wid = tid >> 6;
    const int col  = lane & 15, quad = lane >> 4;

    f32x4 acc[2][8];
#pragma unroll
    for (int mt = 0; mt < 2; ++mt)
#pragma unroll
        for (int nt = 0; nt < 8; ++nt) acc[mt][nt] = f32x4{0.f, 0.f, 0.f, 0.f};

    __syncthreads();   // gix/bias visible

#pragma unroll
    for (int half = 0; half < 2; ++half) {
        // Stage this K-half: 2048 float4 chunks each for A and W.
#pragma unroll
        for (int it = 0; it < 8; ++it) {
            int c   = it * 256 + tid;   // 0..2047
            int row = c >> 4;           // 0..127
            int seg = c & 15;           // float4 within the 64-col half

            float4 wv = ((const float4*)Wih)[row * 32 + half * 16 + seg];
            bf16x4 wh, wl;
            wh[0] = (__bf16)wv.x; wl[0] = (__bf16)(wv.x - (float)wh[0]);
            wh[1] = (__bf16)wv.y; wl[1] = (__bf16)(wv.y - (float)wh[1]);
            wh[2] = (__bf16)wv.z; wl[2] = (__bf16)(wv.z - (float)wh[2]);
            wh[3] = (__bf16)wv.w; wl[3] = (__bf16)(wv.w - (float)wh[3]);
            *(bf16x4*)&Wh[row * LDA + seg * 4] = wh;
            *(bf16x4*)&Wl[row * LDA + seg * 4] = wl;

            int gi = gix[row];
            float4 av = ((const float4*)emb)[(size_t)gi * 32 + half * 16 + seg];
            bf16x4 ah, al;
            ah[0] = (__bf16)av.x; al[0] = (__bf16)(av.x - (float)ah[0]);
            ah[1] = (__bf16)av.y; al[1] = (__bf16)(av.y - (float)ah[1]);
            ah[2] = (__bf16)av.z; al[2] = (__bf16)(av.z - (float)ah[2]);
            ah[3] = (__bf16)av.w; al[3] = (__bf16)(av.w - (float)ah[3]);
            *(bf16x4*)&Ah[row * LDA + seg * 4] = ah;
            *(bf16x4*)&Al[row * LDA + seg * 4] = al;
        }
        __syncthreads();   // staged data visible

#pragma unroll
        for (int kk = 0; kk < 2; ++kk) {  // K steps of 32 within the half
            bf16x8 afh[2], afl[2];
#pragma unroll
            for (int mt = 0; mt < 2; ++mt) {
                int ro = (wid * 32 + mt * 16 + col) * LDA + kk * 32 + quad * 8;
                afh[mt] = *(const bf16x8*)&Ah[ro];
                afl[mt] = *(const bf16x8*)&Al[ro];
            }
#pragma unroll
            for (int nt = 0; nt < 8; ++nt) {
                int ro = (nt * 16 + col) * LDA + kk * 32 + quad * 8;
                bf16x8 wfh = *(const bf16x8*)&Wh[ro];
                bf16x8 wfl = *(const bf16x8*)&Wl[ro];
#pragma unroll
                for (int mt = 0; mt < 2; ++mt) {
                    acc[mt][nt] = __builtin_amdgcn_mfma_f32_16x16x32_bf16(afh[mt], wfh, acc[mt][nt], 0, 0, 0);
                    acc[mt][nt] = __builtin_amdgcn_mfma_f32_16x16x32_bf16(afl[mt], wfh, acc[mt][nt], 0, 0, 0);
                    acc[mt][nt] = __builtin_amdgcn_mfma_f32_16x16x32_bf16(afh[mt], wfl, acc[mt][nt], 0, 0, 0);
                }
            }
        }
        if (half == 0) __syncthreads();   // MFMA reads done before restage
    }

    // Epilogue: C/D layout col=lane&15, row=(lane>>4)*4+reg  [verified m89/m91]
#pragma unroll
    for (int mt = 0; mt < 2; ++mt) {
#pragma unroll
        for (int nt = 0; nt < 8; ++nt) {
            int m = m0 + wid * 32 + mt * 16 + quad * 4;
            int n = nt * 16 + col;
            float bs = bias_s[n];
#pragma unroll
            for (int r = 0; r < 4; ++r)
                xpout[(size_t)(m + r) * 128 + n] = (XPT)(acc[mt][nt][r] + bs);
        }
    }
}

// ---------------------------------------------------------------------------
// Kernel 2: sequential scan  h = tanh(x_proj[t] + W_hh @ h)   (512 steps)
// RESTRUCTURED (round 5): wave w owns OUTPUTS [32w,32w+32) with full K,
// K split only 2-way inside the wave: lane = kh*32+o computes output 32w+o
// over K-half [64kh, 64kh+64). The cross-wave LDS-partials round trip and
// barrier #2 are gone: one __shfl_xor(p,32) does the K-reduce in-register,
// h_s is double-buffered so ONE __syncthreads per step suffices.
// Old critical path/step ~795 cy (2 barriers, 2 LDS round trips, tid<128
// serial tail); new ~370 cy (1 barrier, 1 broadcast read, in-wave reduce).
// ---------------------------------------------------------------------------
template <typename XPT>
__global__ __launch_bounds__(256, 1) void rnn_scan(
    const XPT* __restrict__ xp, const float* __restrict__ Whh,
    const float* __restrict__ h0, float* __restrict__ hlast)
{
    const int b    = blockIdx.x;
    const int tid  = threadIdx.x;
    const int w    = tid >> 6;       // wave id: owns outputs [32w, 32w+32)
    const int lane = tid & 63;
    const int o    = lane & 31;      // output index within wave's slice
    const int kh   = lane >> 5;      // K-half: [64kh, 64kh+64)

    __shared__ float h_s[2][128];    // double buffer -> 1 barrier/step

    // Weights: row (32w+o), K-slice [64kh, 64kh+64) as 16 float4 (64 VGPRs).
    f32x4 wv[16];
    {
        const float* r = Whh + (size_t)(w * 32 + o) * 128 + kh * 64;
#pragma unroll
        for (int c = 0; c < 16; ++c) wv[c] = *(const f32x4*)(r + c * 4);
    }
    // Pin: asm result cannot be rematerialized -> weights stay in VGPRs
    // (round-4 counters showed VGPR_Count=52: compiler was re-fetching).
#pragma unroll
    for (int c = 0; c < 16; ++c) asm volatile("" : "+v"(wv[c]));

    if (tid < 128) h_s[0][tid] = h0[b * 128 + tid];

    // x_proj register ring: 8 steps ahead (all lanes; both K-halves load the
    // same value for output 32w+o -- redundant but branch-free).
    const XPT* xpb  = xp + (size_t)b * (TT * 128);
    const int  xoff = w * 32 + o;
    float xv[8];
#pragma unroll
    for (int s = 0; s < 8; ++s) xv[s] = (float)xpb[s * 128 + xoff];
    __syncthreads();

    int cur = 0;
    for (int tw = 0; tw < TT; tw += 8) {
#pragma unroll
        for (int ts = 0; ts < 8; ++ts) {
            // broadcast read of this lane's K-half of h (uniform per
            // half-wave -> 2-way aliasing = conflict-free)
            const float* hq = &h_s[cur][kh * 64];
            f32x4 h4[16];
#pragma unroll
            for (int u = 0; u < 16; ++u) h4[u] = *(const f32x4*)&hq[u * 4];

            f32x4 aA = f32x4{0.f, 0.f, 0.f, 0.f};
            f32x4 aB = f32x4{0.f, 0.f, 0.f, 0.f};
#pragma unroll
            for (int u = 0; u < 8; ++u) {
                aA += wv[u]     * h4[u];
                aB += wv[u + 8] * h4[u + 8];
            }
            f32x4 at = aA + aB;
            float p  = (at[0] + at[1]) + (at[2] + at[3]);
            // K-reduce across the two halves: one cross-lane op, no LDS.
            p += __shfl_xor(p, 32, 64);
            float hnew = fast_tanh(p + xv[ts]);

            if (lane < 32) h_s[cur ^ 1][w * 32 + o] = hnew;
            // refill ring slot for step tw+8+ts (latency hidden 8 steps)
            if (tw + 8 < TT)
                xv[ts] = (float)xpb[(size_t)(tw + 8 + ts) * 128 + xoff];
            __syncthreads();
            cur ^= 1;
        }
    }
    if (tid < 128) hlast[b * 128 + tid] = h_s[cur][tid];
}

// ---------------------------------------------------------------------------
// Kernel 3: MLP head. hidden = relu(h @ W1^T + b1) [256]; logits = hidden @ W2^T + b2 [4]
// One block per batch row. Also writes last_hidden to d_out. (unchanged)
// ---------------------------------------------------------------------------
__global__ __launch_bounds__(256, 2) void mlp_head(
    const float* __restrict__ hlast, const float* __restrict__ W1,
    const float* __restrict__ b1, const float* __restrict__ W2,
    const float* __restrict__ b2, float* __restrict__ out)
{
    const int b = blockIdx.x, tid = threadIdx.x;
    __shared__ float h_row[128];
    __shared__ float hid[256];

    if (tid < 128) {
        float hv = hlast[b * 128 + tid];
        h_row[tid] = hv;
        out[1024 + b * 128 + tid] = hv;   // last_hidden output (fp32)
    }
    __syncthreads();

    // hidden[tid] = relu(b1[tid] + sum_k W1[tid][k] * h[k]); W1 from L2
    {
        float acc = b1[tid];
        const float4* wrow = (const float4*)(W1 + (size_t)tid * 128);
#pragma unroll
        for (int k4 = 0; k4 < 32; ++k4) {
            float4 wv = wrow[k4];
            acc += wv.x * h_row[k4 * 4 + 0] + wv.y * h_row[k4 * 4 + 1]
                 + wv.z * h_row[k4 * 4 + 2] + wv.w * h_row[k4 * 4 + 3];
        }
        hid[tid] = fmaxf(acc, 0.f);
    }
    __syncthreads();

    // logits: wave w -> class w; 64-lane strided partials + shuffle reduce
    const int wv = tid >> 6, lane = tid & 63;
    float s = 0.f;
#pragma unroll
    for (int qq = 0; qq < 4; ++qq)
        s += hid[qq * 64 + lane] * W2[wv * 256 + qq * 64 + lane];
#pragma unroll
    for (int off = 32; off > 0; off >>= 1) s += __shfl_down(s, off);
    if (lane == 0) out[b * 4 + wv] = s + b2[wv];
}

// ---------------------------------------------------------------------------
extern "C" void kernel_launch(void* const* d_in, const int* in_sizes, int n_in,
                              void* d_out, int out_size, void* d_ws, size_t ws_size,
                              hipStream_t stream)
{
    const int*   x   = (const int*)d_in[0];
    const float* h0  = (const float*)d_in[1];
    const float* emb = (const float*)d_in[2];
    const float* Wih = (const float*)d_in[3];
    const float* Whh = (const float*)d_in[4];
    const float* bih = (const float*)d_in[5];
    const float* bhh = (const float*)d_in[6];
    const float* W1  = (const float*)d_in[7];
    const float* b1  = (const float*)d_in[8];
    const float* W2  = (const float*)d_in[9];
    const float* b2  = (const float*)d_in[10];
    float* out = (float*)d_out;

    const size_t xp_f32_bytes = (size_t)MM * 128 * sizeof(float);   // 64 MB
    const size_t hl_bytes     = (size_t)BB * 128 * sizeof(float);   // 128 KB

    if (ws_size >= xp_f32_bytes + hl_bytes) {
        float* xpw = (float*)d_ws;
        float* hl  = (float*)((char*)d_ws + xp_f32_bytes);
        embed_gemm<float><<<MM / 128, 256, 0, stream>>>(x, emb, Wih, bih, bhh, xpw);
        rnn_scan<float><<<BB, 256, 0, stream>>>(xpw, Whh, h0, hl);
        mlp_head<<<BB, 256, 0, stream>>>(hl, W1, b1, W2, b2, out);
    } else {
        // Fallback: bf16 x_proj storage (32 MB) if workspace is small
        __bf16* xpw = (__bf16*)d_ws;
        float*  hl  = (float*)((char*)d_ws + (size_t)MM * 128 * sizeof(__bf16));
        embed_gemm<__bf16><<<MM / 128, 256, 0, stream>>>(x, emb, Wih, bih, bhh, xpw);
        rnn_scan<__bf16><<<BB, 256, 0, stream>>>(xpw, Whh, h0, hl);
        mlp_head<<<BB, 256, 0, stream>>>(hl, W1, b1, W2, b2, out);
    }
}

// Round 2
// 283.371 us; speedup vs baseline: 1.0067x; 1.0067x over previous
//
#include <hip/hip_runtime.h>
#include <hip/hip_bf16.h>
#include <math.h>

// Problem constants
#define BB 256
#define TT 512
#define EE 128
#define HH 128
#define NC 4
#define MM (BB * TT)   // 131072 rows of the input GEMM

typedef __bf16 bf16x8 __attribute__((ext_vector_type(8)));
typedef __bf16 bf16x4 __attribute__((ext_vector_type(4)));
typedef float  f32x4  __attribute__((ext_vector_type(4)));
typedef float  f32x2  __attribute__((ext_vector_type(2)));

// Branch-free tanh: 1 - 2/(1+e^{2x}) with e^{2x} = exp2(2*log2e*x).
__device__ __forceinline__ float fast_tanh(float x) {
    float t = __builtin_amdgcn_exp2f(x * 2.885390081777927f);
    return 1.f - 2.f * __builtin_amdgcn_rcpf(1.f + t);
}

// Workgroup barrier that does NOT drain vmcnt (unlike __syncthreads, which
// emits s_waitcnt vmcnt(0) lgkmcnt(0) before s_barrier). LDS ordering needs
// only lgkmcnt(0); global prefetch loads stay in flight across steps.
// "memory" clobbers pin ds ops on their side of the barrier.
__device__ __forceinline__ void lds_barrier() {
    asm volatile("s_waitcnt lgkmcnt(0)" ::: "memory");
    __builtin_amdgcn_s_barrier();
    asm volatile("" ::: "memory");
}

// ---------------------------------------------------------------------------
// Kernel 1: x_proj[m,h] = sum_e emb[x[m],e] * W_ih[h,e] + b_ih[h] + b_hh[h]
// Split-bf16 GEMM (AhWh + AlWh + AhWl). K processed in 2 halves of 64 with
// half-size LDS buffers (~74 KB total) so 2 blocks/CU actually fit.
// (unchanged this round)
// ---------------------------------------------------------------------------
template <typename XPT>
__global__ __launch_bounds__(256, 2) void embed_gemm(
    const int* __restrict__ x, const float* __restrict__ emb,
    const float* __restrict__ Wih, const float* __restrict__ bih,
    const float* __restrict__ bhh, XPT* __restrict__ xpout)
{
    const int tid = threadIdx.x;
    const int m0  = blockIdx.x * 128;

    const int LDA = 72;  // bf16 units per 64-wide half row (144 B, 16B-aligned)
    __shared__ __bf16 Ah[128 * 72];
    __shared__ __bf16 Al[128 * 72];
    __shared__ __bf16 Wh[128 * 72];
    __shared__ __bf16 Wl[128 * 72];
    __shared__ float  bias_s[128];
    __shared__ int    gix[128];

    if (tid < 128) {
        gix[tid]    = x[m0 + tid];
        bias_s[tid] = bih[tid] + bhh[tid];
    }

    const int lane = tid & 63, wid = tid >> 6;
    const int col  = lane & 15, quad = lane >> 4;

    f32x4 acc[2][8];
#pragma unroll
    for (int mt = 0; mt < 2; ++mt)
#pragma unroll
        for (int nt = 0; nt < 8; ++nt) acc[mt][nt] = f32x4{0.f, 0.f, 0.f, 0.f};

    __syncthreads();   // gix/bias visible

#pragma unroll
    for (int half = 0; half < 2; ++half) {
        // Stage this K-half: 2048 float4 chunks each for A and W.
#pragma unroll
        for (int it = 0; it < 8; ++it) {
            int c   = it * 256 + tid;   // 0..2047
            int row = c >> 4;           // 0..127
            int seg = c & 15;           // float4 within the 64-col half

            float4 wv = ((const float4*)Wih)[row * 32 + half * 16 + seg];
            bf16x4 wh, wl;
            wh[0] = (__bf16)wv.x; wl[0] = (__bf16)(wv.x - (float)wh[0]);
            wh[1] = (__bf16)wv.y; wl[1] = (__bf16)(wv.y - (float)wh[1]);
            wh[2] = (__bf16)wv.z; wl[2] = (__bf16)(wv.z - (float)wh[2]);
            wh[3] = (__bf16)wv.w; wl[3] = (__bf16)(wv.w - (float)wh[3]);
            *(bf16x4*)&Wh[row * LDA + seg * 4] = wh;
            *(bf16x4*)&Wl[row * LDA + seg * 4] = wl;

            int gi = gix[row];
            float4 av = ((const float4*)emb)[(size_t)gi * 32 + half * 16 + seg];
            bf16x4 ah, al;
            ah[0] = (__bf16)av.x; al[0] = (__bf16)(av.x - (float)ah[0]);
            ah[1] = (__bf16)av.y; al[1] = (__bf16)(av.y - (float)ah[1]);
            ah[2] = (__bf16)av.z; al[2] = (__bf16)(av.z - (float)ah[2]);
            ah[3] = (__bf16)av.w; al[3] = (__bf16)(av.w - (float)ah[3]);
            *(bf16x4*)&Ah[row * LDA + seg * 4] = ah;
            *(bf16x4*)&Al[row * LDA + seg * 4] = al;
        }
        __syncthreads();   // staged data visible

#pragma unroll
        for (int kk = 0; kk < 2; ++kk) {  // K steps of 32 within the half
            bf16x8 afh[2], afl[2];
#pragma unroll
            for (int mt = 0; mt < 2; ++mt) {
                int ro = (wid * 32 + mt * 16 + col) * LDA + kk * 32 + quad * 8;
                afh[mt] = *(const bf16x8*)&Ah[ro];
                afl[mt] = *(const bf16x8*)&Al[ro];
            }
#pragma unroll
            for (int nt = 0; nt < 8; ++nt) {
                int ro = (nt * 16 + col) * LDA + kk * 32 + quad * 8;
                bf16x8 wfh = *(const bf16x8*)&Wh[ro];
                bf16x8 wfl = *(const bf16x8*)&Wl[ro];
#pragma unroll
                for (int mt = 0; mt < 2; ++mt) {
                    acc[mt][nt] = __builtin_amdgcn_mfma_f32_16x16x32_bf16(afh[mt], wfh, acc[mt][nt], 0, 0, 0);
                    acc[mt][nt] = __builtin_amdgcn_mfma_f32_16x16x32_bf16(afl[mt], wfh, acc[mt][nt], 0, 0, 0);
                    acc[mt][nt] = __builtin_amdgcn_mfma_f32_16x16x32_bf16(afh[mt], wfl, acc[mt][nt], 0, 0, 0);
                }
            }
        }
        if (half == 0) __syncthreads();   // MFMA reads done before restage
    }

    // Epilogue: C/D layout col=lane&15, row=(lane>>4)*4+reg  [verified m89/m91]
#pragma unroll
    for (int mt = 0; mt < 2; ++mt) {
#pragma unroll
        for (int nt = 0; nt < 8; ++nt) {
            int m = m0 + wid * 32 + mt * 16 + quad * 4;
            int n = nt * 16 + col;
            float bs = bias_s[n];
#pragma unroll
            for (int r = 0; r < 4; ++r)
                xpout[(size_t)(m + r) * 128 + n] = (XPT)(acc[mt][nt][r] + bs);
        }
    }
}

// ---------------------------------------------------------------------------
// Kernel 2: sequential scan  h = tanh(x_proj[t] + W_hh @ h)   (512 steps)
// Round 6: the round-5 restructure was correct but neutralized by
// __syncthreads() draining vmcnt(0) at every step -- the x_proj "prefetch"
// ring was serialized onto the critical path (measured 845 cy/step vs ~350
// structural). Fix: raw s_barrier + lgkmcnt-only fence (lds_barrier above),
// so refill loads genuinely stay in flight for 8 steps; the compiler's
// counted vmcnt wait before each xv use has ~2700 cy of slack.
// Structure: wave w owns outputs [32w,32w+32), lane = kh*32+o computes
// output 32w+o over K-half [64kh,64kh+64); one __shfl_xor(32) K-reduce;
// h_s double-buffered with STATIC buffer index (ts&1) -> 1 barrier/step.
// ---------------------------------------------------------------------------
template <typename XPT>
__global__ __launch_bounds__(256, 1) void rnn_scan(
    const XPT* __restrict__ xp, const float* __restrict__ Whh,
    const float* __restrict__ h0, float* __restrict__ hlast)
{
    const int b    = blockIdx.x;
    const int tid  = threadIdx.x;
    const int w    = tid >> 6;       // wave id: owns outputs [32w, 32w+32)
    const int lane = tid & 63;
    const int o    = lane & 31;      // output index within wave's slice
    const int kh   = lane >> 5;      // K-half: [64kh, 64kh+64)

    __shared__ float h_s[2][128];    // double buffer -> 1 barrier/step

    // Weights: row (32w+o), K-slice [64kh, 64kh+64) as 16 float4 (64 VGPRs).
    f32x4 wv[16];
    {
        const float* r = Whh + (size_t)(w * 32 + o) * 128 + kh * 64;
#pragma unroll
        for (int c = 0; c < 16; ++c) wv[c] = *(const f32x4*)(r + c * 4);
    }
    // Pin: asm result cannot be rematerialized -> weights stay in VGPRs
    // (round-4 counters showed VGPR_Count=52: compiler was re-fetching).
#pragma unroll
    for (int c = 0; c < 16; ++c) asm volatile("" : "+v"(wv[c]));

    if (tid < 128) h_s[0][tid] = h0[b * 128 + tid];

    // x_proj register ring: 8 steps ahead.
    const XPT* xpb  = xp + (size_t)b * (TT * 128);
    const int  xoff = w * 32 + o;
    float xv[8];
#pragma unroll
    for (int s = 0; s < 8; ++s) xv[s] = (float)xpb[s * 128 + xoff];
    lds_barrier();

    for (int tw = 0; tw < TT; tw += 8) {
#pragma unroll
        for (int ts = 0; ts < 8; ++ts) {
            const int c = ts & 1;    // static double-buffer index (8 flips/group)
            // broadcast read of this lane's K-half of h (uniform per
            // half-wave -> 2-way aliasing = conflict-free)
            const float* hq = &h_s[c][kh * 64];
            f32x4 h4[16];
#pragma unroll
            for (int u = 0; u < 16; ++u) h4[u] = *(const f32x4*)&hq[u * 4];

            f32x4 aA = f32x4{0.f, 0.f, 0.f, 0.f};
            f32x4 aB = f32x4{0.f, 0.f, 0.f, 0.f};
#pragma unroll
            for (int u = 0; u < 8; ++u) {
                aA += wv[u]     * h4[u];
                aB += wv[u + 8] * h4[u + 8];
            }
            f32x4 at = aA + aB;
            float p  = (at[0] + at[1]) + (at[2] + at[3]);
            // K-reduce across the two halves: one cross-lane op, no LDS.
            p += __shfl_xor(p, 32, 64);
            float hnew = fast_tanh(p + xv[ts]);

            if (lane < 32) h_s[c ^ 1][w * 32 + o] = hnew;
            // refill ring slot for step tw+8+ts; load stays in flight across
            // the raw barriers (no vmcnt drain) for ~8 steps.
            if (tw + 8 < TT)
                xv[ts] = (float)xpb[(size_t)(tw + 8 + ts) * 128 + xoff];
            lds_barrier();
        }
    }
    if (tid < 128) hlast[b * 128 + tid] = h_s[0][tid];
}

// ---------------------------------------------------------------------------
// Kernel 3: MLP head. hidden = relu(h @ W1^T + b1) [256]; logits = hidden @ W2^T + b2 [4]
// One block per batch row. Also writes last_hidden to d_out. (unchanged)
// ---------------------------------------------------------------------------
__global__ __launch_bounds__(256, 2) void mlp_head(
    const float* __restrict__ hlast, const float* __restrict__ W1,
    const float* __restrict__ b1, const float* __restrict__ W2,
    const float* __restrict__ b2, float* __restrict__ out)
{
    const int b = blockIdx.x, tid = threadIdx.x;
    __shared__ float h_row[128];
    __shared__ float hid[256];

    if (tid < 128) {
        float hv = hlast[b * 128 + tid];
        h_row[tid] = hv;
        out[1024 + b * 128 + tid] = hv;   // last_hidden output (fp32)
    }
    __syncthreads();

    // hidden[tid] = relu(b1[tid] + sum_k W1[tid][k] * h[k]); W1 from L2
    {
        float acc = b1[tid];
        const float4* wrow = (const float4*)(W1 + (size_t)tid * 128);
#pragma unroll
        for (int k4 = 0; k4 < 32; ++k4) {
            float4 wv = wrow[k4];
            acc += wv.x * h_row[k4 * 4 + 0] + wv.y * h_row[k4 * 4 + 1]
                 + wv.z * h_row[k4 * 4 + 2] + wv.w * h_row[k4 * 4 + 3];
        }
        hid[tid] = fmaxf(acc, 0.f);
    }
    __syncthreads();

    // logits: wave w -> class w; 64-lane strided partials + shuffle reduce
    const int wv = tid >> 6, lane = tid & 63;
    float s = 0.f;
#pragma unroll
    for (int qq = 0; qq < 4; ++qq)
        s += hid[qq * 64 + lane] * W2[wv * 256 + qq * 64 + lane];
#pragma unroll
    for (int off = 32; off > 0; off >>= 1) s += __shfl_down(s, off);
    if (lane == 0) out[b * 4 + wv] = s + b2[wv];
}

// ---------------------------------------------------------------------------
extern "C" void kernel_launch(void* const* d_in, const int* in_sizes, int n_in,
                              void* d_out, int out_size, void* d_ws, size_t ws_size,
                              hipStream_t stream)
{
    const int*   x   = (const int*)d_in[0];
    const float* h0  = (const float*)d_in[1];
    const float* emb = (const float*)d_in[2];
    const float* Wih = (const float*)d_in[3];
    const float* Whh = (const float*)d_in[4];
    const float* bih = (const float*)d_in[5];
    const float* bhh = (const float*)d_in[6];
    const float* W1  = (const float*)d_in[7];
    const float* b1  = (const float*)d_in[8];
    const float* W2  = (const float*)d_in[9];
    const float* b2  = (const float*)d_in[10];
    float* out = (float*)d_out;

    const size_t xp_f32_bytes = (size_t)MM * 128 * sizeof(float);   // 64 MB
    const size_t hl_bytes     = (size_t)BB * 128 * sizeof(float);   // 128 KB

    if (ws_size >= xp_f32_bytes + hl_bytes) {
        float* xpw = (float*)d_ws;
        float* hl  = (float*)((char*)d_ws + xp_f32_bytes);
        embed_gemm<float><<<MM / 128, 256, 0, stream>>>(x, emb, Wih, bih, bhh, xpw);
        rnn_scan<float><<<BB, 256, 0, stream>>>(xpw, Whh, h0, hl);
        mlp_head<<<BB, 256, 0, stream>>>(hl, W1, b1, W2, b2, out);
    } else {
        // Fallback: bf16 x_proj storage (32 MB) if workspace is small
        __bf16* xpw = (__bf16*)d_ws;
        float*  hl  = (float*)((char*)d_ws + (size_t)MM * 128 * sizeof(__bf16));
        embed_gemm<__bf16><<<MM / 128, 256, 0, stream>>>(x, emb, Wih, bih, bhh, xpw);
        rnn_scan<__bf16><<<BB, 256, 0, stream>>>(xpw, Whh, h0, hl);
        mlp_head<<<BB, 256, 0, stream>>>(hl, W1, b1, W2, b2, out);
    }
}